// Round 6
// baseline (212.086 us; speedup 1.0000x reference)
//
#include <hip/hip_runtime.h>

#define IMG   128
#define KF    4
#define NF    800
#define NV    2000
#define NB    2
#define EPSF  1e-8f
#define BLURF 0.01f
// rect-edge cull: dist>0.1015 => (w/len)^2 > 0.0103 with w<0
#define CULL_D2 0.0103f
#define HEXT    0.0547f   // tile half-extent (7/128) + margin
#define FARC    0.0102f   // conservative "far from all edge lines" gate (vs dd=l+eps)
#define REC     20        // floats per survivor record

typedef unsigned long long u64;
#define INVK ((((u64)0x7f800000u) << 32) | 0xffffffffu)   // z=+inf, idx=-1

// Match numpy: no FMA contraction anywhere on the exact paths.
#pragma clang fp contract(off)

__device__ __forceinline__ void ins4(u64& s0, u64& s1, u64& s2, u64& s3, u64 k) {
    bool c0 = k < s0, c1 = k < s1, c2 = k < s2, c3 = k < s3;
    s3 = c2 ? s2 : (c3 ? k : s3);
    s2 = c1 ? s1 : (c2 ? k : s2);
    s1 = c0 ? s0 : (c1 ? k : s1);
    s0 = c0 ? k  : s0;
}

// ---- kernel 1: persistent waves steal (tile, face-slice) units ----
__global__ __launch_bounds__(256) void raster_p1(
    const float* __restrict__ verts,   // (B, V, 3)
    const int*   __restrict__ faces,   // (F, 3)
    unsigned*    __restrict__ cnt,     // steal counter (memset to 0)
    u64*         __restrict__ part,    // [512*S][4][64] partial keys
    int sh)                            // log2(slices per tile)
{
#pragma clang fp contract(off)
    __shared__ float sv[4][100 * REC];   // per-wave survivor records (32 KB max)

    const int S     = 1 << sh;
    const int chunk = NF >> sh;          // 50 (sh=4) or 100 (sh=3)
    const int NU    = 512 << sh;
    const int wave  = threadIdx.x >> 6;
    const int lane  = threadIdx.x & 63;
    float* svw = sv[wave];

    for (;;) {
        unsigned u = 0;
        if (lane == 0) u = atomicAdd(cnt, 1u);
        u = (unsigned)__shfl((int)u, 0);
        if (u >= (unsigned)NU) break;

        const int tile  = (int)u >> sh;
        const int slice = (int)u & (S - 1);
        const int b     = tile >> 8;
        const int trow  = (tile & 255) >> 4;
        const int tcol  = tile & 15;
        const float* vb = verts + b * NV * 3;
        const int fbase = slice * chunk;

        // per-lane pixel geometry (8x8 tile)
        const int pr = lane >> 3, pc = lane & 7;
        const int row = trow * 8 + pr, col = tcol * 8 + pc;
        const float px = 1.0f - (2.0f * ((float)col + 0.5f)) / 128.0f;
        const float py = 1.0f - (2.0f * ((float)row + 0.5f)) / 128.0f;
        const float txmax = 1.0f - (2.0f * ((float)(tcol * 8)     + 0.5f)) / 128.0f;
        const float txmin = 1.0f - (2.0f * ((float)(tcol * 8 + 7) + 0.5f)) / 128.0f;
        const float tymax = 1.0f - (2.0f * ((float)(trow * 8)     + 0.5f)) / 128.0f;
        const float tymin = 1.0f - (2.0f * ((float)(trow * 8 + 7) + 0.5f)) / 128.0f;
        const float cx = 0.5f * (txmin + txmax);
        const float cy = 0.5f * (tymin + tymax);

        // ---- cull + compact survivor records into per-wave LDS ----
        int scnt = 0;
        for (int fo = 0; fo < chunk; fo += 64) {
            const int fl = fo + lane;
            bool surv = false;
            float a0x=0,a0y=0,a1x=0,a1y=0,a2x=0,a2y=0,z0=0,z1=0,z2=0,denom=1;
            float e0x=0,e0y=0,e1x=0,e1y=0,e2x=0,e2y=0;
            if (fl < chunk) {
                const int f = fbase + fl;
                int i0 = faces[3*f+0], i1 = faces[3*f+1], i2 = faces[3*f+2];
                a0x = vb[3*i0]; a0y = vb[3*i0+1]; z0 = vb[3*i0+2];
                a1x = vb[3*i1]; a1y = vb[3*i1+1]; z1 = vb[3*i1+2];
                a2x = vb[3*i2]; a2y = vb[3*i2+1]; z2 = vb[3*i2+2];
                // numpy op order for area (exact-match)
                float area = (a2x - a0x) * (a1y - a0y) - (a2y - a0y) * (a1x - a0x);
                float aab  = fabsf(area);
                denom = (aab > EPSF) ? area : (area >= 0.0f ? EPSF : -EPSF);
                surv = aab > EPSF;
                float bxmin = fminf(a0x, fminf(a1x, a2x)) - 0.101f;
                float bxmax = fmaxf(a0x, fmaxf(a1x, a2x)) + 0.101f;
                float bymin = fminf(a0y, fminf(a1y, a2y)) - 0.101f;
                float bymax = fmaxf(a0y, fmaxf(a1y, a2y)) + 0.101f;
                surv &= !(bxmin > txmax || bxmax < txmin || bymin > tymax || bymax < tymin);
                // exact rect-vs-edge-line cull (conservative)
                float s = (area >= 0.0f) ? 1.0f : -1.0f;
                e0x = a2x - a1x; e0y = a2y - a1y;
                e1x = a0x - a2x; e1y = a0y - a2y;
                e2x = a1x - a0x; e2y = a1y - a0y;
                float w0 = s * ((cx - a1x) * e0y - (cy - a1y) * e0x) + HEXT * (fabsf(e0x) + fabsf(e0y));
                float w1 = s * ((cx - a2x) * e1y - (cy - a2y) * e1x) + HEXT * (fabsf(e1x) + fabsf(e1y));
                float w2 = s * ((cx - a0x) * e2y - (cy - a0y) * e2x) + HEXT * (fabsf(e2x) + fabsf(e2y));
                float l0 = e0x * e0x + e0y * e0y;
                float l1 = e1x * e1x + e1y * e1y;
                float l2 = e2x * e2x + e2y * e2y;
                surv &= !((w0 < 0.0f) & (w0 * w0 > CULL_D2 * l0));
                surv &= !((w1 < 0.0f) & (w1 * w1 > CULL_D2 * l1));
                surv &= !((w2 < 0.0f) & (w2 * w2 > CULL_D2 * l2));
            }
            u64 m = __ballot(surv);
            if (surv) {
                int pos = scnt + __popcll(m & ((1ull << lane) - 1ull));
                float* r = &svw[pos * REC];
                r[0]=a0x; r[1]=a0y; r[2]=a1x; r[3]=a1y; r[4]=a2x; r[5]=a2y;
                r[6]=e0x; r[7]=e0y; r[8]=e1x; r[9]=e1y; r[10]=e2x; r[11]=e2y;
                r[12]=z0; r[13]=z1; r[14]=z2; r[15]=denom;
                // exact dd for the three segment tests (numpy op order):
                r[16] = (e2x * e2x + e2y * e2y) + EPSF;   // seg(a0,a1)
                r[17] = (e0x * e0x + e0y * e0y) + EPSF;   // seg(a1,a2)
                r[18] = (e1x * e1x + e1y * e1y) + EPSF;   // seg(a2,a0)
                r[19] = __int_as_float(fbase + fl);
            }
            scnt += __popcll(m);
        }

        // ---- eval survivors: wave-uniform LDS broadcast ----
        u64 s0 = INVK, s1 = INVK, s2 = INVK, s3 = INVK;
        for (int j = 0; j < scnt; ++j) {
            const float* r = &svw[j * REC];
            float4 q0 = *(const float4*)(r);
            float4 q1 = *(const float4*)(r + 4);
            float4 q2 = *(const float4*)(r + 8);
            float4 q3 = *(const float4*)(r + 12);
            float4 q4 = *(const float4*)(r + 16);
            float a0x=q0.x, a0y=q0.y, a1x=q0.z, a1y=q0.w, a2x=q1.x, a2y=q1.y;
            float e0x=q1.z, e0y=q1.w, e1x=q2.x, e1y=q2.y, e2x=q2.z, e2y=q2.w;
            float z0=q3.x, z1=q3.y, z2=q3.z, D=q3.w;
            float ddA=q4.x, ddB=q4.y, ddC=q4.z;
            int   fg = __float_as_int(q4.w);
            float p0x = px - a0x, p0y = py - a0y;
            float p1x = px - a1x, p1y = py - a1y;
            float p2x = px - a2x, p2y = py - a2y;
            float w0 = p1x * e0y - p1y * e0x;
            float w1 = p2x * e1y - p2y * e1x;
            float w2 = p0x * e2y - p0y * e2x;
            float b0 = w0 / D, b1 = w1 / D, b2 = w2 / D;    // IEEE divides
            float zpix = (b0 * z0 + b1 * z1) + b2 * z2;     // numpy order
            bool inside = fminf(b0, fminf(b1, b2)) >= 0.0f; // no NaNs possible
            // far gate: all three edge-line dist^2 provably > BLUR (conservative)
            bool far = (w0 * w0 > FARC * ddB) & (w1 * w1 > FARC * ddC) & (w2 * w2 > FARC * ddA);
            bool valid;
            if (__all(inside | far)) {
                valid = inside & (zpix > EPSF);
            } else {
                // seg(a0,a1): pa=p0, ab=e2, dd=ddA
                float tA = (p0x * e2x + p0y * e2y) / ddA;
                tA = fminf(fmaxf(tA, 0.0f), 1.0f);
                float dxA = p0x - tA * e2x, dyA = p0y - tA * e2y;
                float dA = dxA * dxA + dyA * dyA;
                // seg(a1,a2): pa=p1, ab=e0, dd=ddB
                float tB = (p1x * e0x + p1y * e0y) / ddB;
                tB = fminf(fmaxf(tB, 0.0f), 1.0f);
                float dxB = p1x - tB * e0x, dyB = p1y - tB * e0y;
                float dB = dxB * dxB + dyB * dyB;
                // seg(a2,a0): pa=p2, ab=e1, dd=ddC
                float tC = (p2x * e1x + p2y * e1y) / ddC;
                tC = fminf(fmaxf(tC, 0.0f), 1.0f);
                float dxC = p2x - tC * e1x, dyC = p2y - tC * e1y;
                float dC = dxC * dxC + dyC * dyC;
                float dmin = fminf(dA, fminf(dB, dC));
                valid = (inside | (dmin < BLURF)) & (zpix > EPSF);
            }
            u64 key = valid ? ((((u64)__float_as_uint(zpix)) << 32) | (unsigned)fg) : INVK;
            if (__any(key < s3)) ins4(s0, s1, s2, s3, key);
        }

        u64* wrow = part + (size_t)u * 256;
        wrow[0 * 64 + lane] = s0;
        wrow[1 * 64 + lane] = s1;
        wrow[2 * 64 + lane] = s2;
        wrow[3 * 64 + lane] = s3;
    }
}

// ---------------- kernel 2: merge slices + exact epilogue ----------------
__global__ __launch_bounds__(256) void raster_p2(
    const float* __restrict__ verts,
    const int*   __restrict__ faces,
    const u64* __restrict__ part,
    int sh,
    float* __restrict__ out0, float* __restrict__ out1,
    float* __restrict__ out2, float* __restrict__ out3)
{
#pragma clang fp contract(off)
    __shared__ u64 sK[4 * 64];
    const int S    = 1 << sh;
    const int tid  = threadIdx.x;
    const int tile = blockIdx.x;
    const int b    = tile >> 8;
    const int trow = (tile & 255) >> 4;
    const int tcol = tile & 15;
    const float* vb = verts + b * NV * 3;

    if (tid < 64) {
        u64 s0 = INVK, s1 = INVK, s2 = INVK, s3 = INVK;
        const u64* base = part + (size_t)tile * S * 256;
        for (int s = 0; s < S; ++s) {
            ins4(s0, s1, s2, s3, base[s * 256 + 0 * 64 + tid]);
            ins4(s0, s1, s2, s3, base[s * 256 + 1 * 64 + tid]);
            ins4(s0, s1, s2, s3, base[s * 256 + 2 * 64 + tid]);
            ins4(s0, s1, s2, s3, base[s * 256 + 3 * 64 + tid]);
        }
        sK[0 * 64 + tid] = s0;
        sK[1 * 64 + tid] = s1;
        sK[2 * 64 + tid] = s2;
        sK[3 * 64 + tid] = s3;
    }
    __syncthreads();

    int pix = tid >> 2, k = tid & 3;
    u64 key = sK[k * 64 + pix];
    int prow = pix >> 3, pcol = pix & 7;
    int grow = trow * 8 + prow, gcol = tcol * 8 + pcol;
    int p = (b * IMG + grow) * IMG + gcol;
    float qx = 1.0f - (2.0f * ((float)gcol + 0.5f)) / 128.0f;
    float qy = 1.0f - (2.0f * ((float)grow + 0.5f)) / 128.0f;
    float o0 = -1.0f, o1 = -1.0f, ob0 = -1.0f, ob1 = -1.0f, ob2 = -1.0f, o3 = -1.0f;
    if ((unsigned)(key >> 32) != 0x7f800000u) {
        int fi = (int)(unsigned)(key & 0xffffffffu);
        int i0 = faces[3 * fi + 0], i1 = faces[3 * fi + 1], i2 = faces[3 * fi + 2];
        float a0x = vb[3 * i0], a0y = vb[3 * i0 + 1], z0 = vb[3 * i0 + 2];
        float a1x = vb[3 * i1], a1y = vb[3 * i1 + 1], z1 = vb[3 * i1 + 2];
        float a2x = vb[3 * i2], a2y = vb[3 * i2 + 1], z2 = vb[3 * i2 + 2];
        float area = (a2x - a0x) * (a1y - a0y) - (a2y - a0y) * (a1x - a0x);
        float aab  = fabsf(area);
        float denom = (aab > EPSF) ? area : (area >= 0.0f ? EPSF : -EPSF);
        float e0x = a2x - a1x, e0y = a2y - a1y;
        float e1x = a0x - a2x, e1y = a0y - a2y;
        float e2x = a1x - a0x, e2y = a1y - a0y;
        float p0x = qx - a0x, p0y = qy - a0y;
        float p1x = qx - a1x, p1y = qy - a1y;
        float p2x = qx - a2x, p2y = qy - a2y;
        float w0 = p1x * e0y - p1y * e0x;
        float w1 = p2x * e1y - p2y * e1x;
        float w2 = p0x * e2y - p0y * e2x;
        float b0 = w0 / denom, b1 = w1 / denom, b2 = w2 / denom;
        float zpix = (b0 * z0 + b1 * z1) + b2 * z2;
        bool inside = (b0 >= 0.0f) & (b1 >= 0.0f) & (b2 >= 0.0f);
        float ddA = (e2x * e2x + e2y * e2y) + EPSF;
        float tA = (p0x * e2x + p0y * e2y) / ddA;
        tA = fminf(fmaxf(tA, 0.0f), 1.0f);
        float dxA = p0x - tA * e2x, dyA = p0y - tA * e2y;
        float dA = dxA * dxA + dyA * dyA;
        float ddB = (e0x * e0x + e0y * e0y) + EPSF;
        float tB = (p1x * e0x + p1y * e0y) / ddB;
        tB = fminf(fmaxf(tB, 0.0f), 1.0f);
        float dxB = p1x - tB * e0x, dyB = p1y - tB * e0y;
        float dB = dxB * dxB + dyB * dyB;
        float ddC = (e1x * e1x + e1y * e1y) + EPSF;
        float tC = (p2x * e1x + p2y * e1y) / ddC;
        tC = fminf(fmaxf(tC, 0.0f), 1.0f);
        float dxC = p2x - tC * e1x, dyC = p2y - tC * e1y;
        float dC = dxC * dxC + dyC * dyC;
        float dmin = fminf(dA, fminf(dB, dC));
        o0 = (float)fi;
        o1 = zpix;
        ob0 = b0; ob1 = b1; ob2 = b2;
        o3 = inside ? -dmin : dmin;
    }
    int o = p * KF + k;
    out0[o] = o0;
    out1[o] = o1;
    out2[o * 3 + 0] = ob0;
    out2[o * 3 + 1] = ob1;
    out2[o * 3 + 2] = ob2;
    out3[o] = o3;
}

extern "C" void kernel_launch(void* const* d_in, const int* in_sizes, int n_in,
                              void* d_out, int out_size, void* d_ws, size_t ws_size,
                              hipStream_t stream) {
    const float* verts = (const float*)d_in[0];
    const int*   faces = (const int*)d_in[1];
    float* out = (float*)d_out;
    const int n0 = NB * IMG * IMG * KF;   // 131072 per (B,H,W,K) output

    // ws layout: [0,4) steal counter; [4096, ...) partial keys (2 KB per unit).
    const size_t per_unit = 256 * sizeof(u64);
    int sh = (ws_size >= 4096 + (512ull << 4) * per_unit) ? 4    // 16 slices of 50 (16 MB)
           : 3;                                                  //  8 slices of 100 (8 MB)
    unsigned* cnt = (unsigned*)d_ws;
    u64* part = (u64*)((char*)d_ws + 4096);

    hipMemsetAsync(d_ws, 0, 4, stream);
    raster_p1<<<dim3(1024), dim3(256), 0, stream>>>(verts, faces, cnt, part, sh);
    raster_p2<<<dim3(512), dim3(256), 0, stream>>>(verts, faces, part, sh,
        out,                 // pix_to_face
        out + n0,            // zbuf
        out + 2 * n0,        // bary
        out + 5 * n0);       // dsign
}

// Round 7
// 95.606 us; speedup vs baseline: 2.2183x; 2.2183x over previous
//
#include <hip/hip_runtime.h>

#define IMG   128
#define KF    4
#define NF    800
#define NV    2000
#define NB    2
#define EPSF  1e-8f
#define BLURF 0.01f
// rect-edge cull: dist>0.1015 => (w/len)^2 > 0.0103 with w<0
#define CULL_D2 0.0103f
#define HEXT    0.0547f   // tile half-extent (7/128) + margin
#define FARC    0.0102f   // conservative "far from all edge lines" gate (vs dd=l+eps)
#define REC     20        // floats per survivor record (5 x float4)

typedef unsigned long long u64;
#define INVK ((((u64)0x7f800000u) << 32) | 0xffffffffu)   // z=+inf, idx=-1

// Match numpy: no FMA contraction anywhere on the exact paths.
#pragma clang fp contract(off)

__device__ __forceinline__ void ins4(u64& s0, u64& s1, u64& s2, u64& s3, u64 k) {
    bool c0 = k < s0, c1 = k < s1, c2 = k < s2, c3 = k < s3;
    s3 = c2 ? s2 : (c3 ? k : s3);
    s2 = c1 ? s1 : (c2 ? k : s2);
    s1 = c0 ? s0 : (c1 ? k : s1);
    s0 = c0 ? k  : s0;
}

// ---- kernel 1: one block = one (tile, face-slice) unit; static grid ----
__global__ __launch_bounds__(256) void raster_p1(
    const float* __restrict__ verts,   // (B, V, 3)
    const int*   __restrict__ faces,   // (F, 3)
    u64*         __restrict__ part,    // [512*S][4][64] partial keys
    int sh)                            // log2(slices per tile)
{
#pragma clang fp contract(off)
    extern __shared__ float sFD[];       // [chunk * REC] survivor records
    __shared__ u64 sK[2 * 4 * 64];       // cross-wave merge rows (4 KB)
    __shared__ unsigned sWc[4];

    const int S     = 1 << sh;
    const int chunk = NF >> sh;          // 100 (sh=3) or 200 (sh=2)
    const int tid   = threadIdx.x;
    const int wave  = tid >> 6;
    const int lane  = tid & 63;
    const int unit  = blockIdx.x;        // [0, 512*S)
    const int tile  = unit >> sh;
    const int slice = unit & (S - 1);
    const int b     = tile >> 8;
    const int trow  = (tile & 255) >> 4;
    const int tcol  = tile & 15;
    const float* vb = verts + b * NV * 3;
    const int fbase = slice * chunk;

    // per-lane pixel geometry (8x8 tile)
    const int pr = lane >> 3, pc = lane & 7;
    const int row = trow * 8 + pr, col = tcol * 8 + pc;
    const float px = 1.0f - (2.0f * ((float)col + 0.5f)) / 128.0f;
    const float py = 1.0f - (2.0f * ((float)row + 0.5f)) / 128.0f;
    const float txmax = 1.0f - (2.0f * ((float)(tcol * 8)     + 0.5f)) / 128.0f;
    const float txmin = 1.0f - (2.0f * ((float)(tcol * 8 + 7) + 0.5f)) / 128.0f;
    const float tymax = 1.0f - (2.0f * ((float)(trow * 8)     + 0.5f)) / 128.0f;
    const float tymin = 1.0f - (2.0f * ((float)(trow * 8 + 7) + 0.5f)) / 128.0f;
    const float cx = 0.5f * (txmin + txmax);
    const float cy = 0.5f * (tymin + tymax);

    // ---- cooperative cull + ballot compaction into records (no atomics) ----
    int scnt = 0;
    for (int j0 = 0; j0 < chunk; j0 += 256) {
        const int jl = j0 + tid;
        bool surv = false;
        float a0x=0,a0y=0,a1x=0,a1y=0,a2x=0,a2y=0,z0=0,z1=0,z2=0,denom=1;
        float e0x=0,e0y=0,e1x=0,e1y=0,e2x=0,e2y=0;
        if (jl < chunk) {
            const int f = fbase + jl;
            int i0 = faces[3*f+0], i1 = faces[3*f+1], i2 = faces[3*f+2];
            a0x = vb[3*i0]; a0y = vb[3*i0+1]; z0 = vb[3*i0+2];
            a1x = vb[3*i1]; a1y = vb[3*i1+1]; z1 = vb[3*i1+2];
            a2x = vb[3*i2]; a2y = vb[3*i2+1]; z2 = vb[3*i2+2];
            // numpy op order for area (exact-match)
            float area = (a2x - a0x) * (a1y - a0y) - (a2y - a0y) * (a1x - a0x);
            float aab  = fabsf(area);
            denom = (aab > EPSF) ? area : (area >= 0.0f ? EPSF : -EPSF);
            surv = aab > EPSF;
            float bxmin = fminf(a0x, fminf(a1x, a2x)) - 0.101f;
            float bxmax = fmaxf(a0x, fmaxf(a1x, a2x)) + 0.101f;
            float bymin = fminf(a0y, fminf(a1y, a2y)) - 0.101f;
            float bymax = fmaxf(a0y, fmaxf(a1y, a2y)) + 0.101f;
            surv &= !(bxmin > txmax || bxmax < txmin || bymin > tymax || bymax < tymin);
            // exact rect-vs-edge-line cull (conservative)
            float s = (area >= 0.0f) ? 1.0f : -1.0f;
            e0x = a2x - a1x; e0y = a2y - a1y;
            e1x = a0x - a2x; e1y = a0y - a2y;
            e2x = a1x - a0x; e2y = a1y - a0y;
            float w0 = s * ((cx - a1x) * e0y - (cy - a1y) * e0x) + HEXT * (fabsf(e0x) + fabsf(e0y));
            float w1 = s * ((cx - a2x) * e1y - (cy - a2y) * e1x) + HEXT * (fabsf(e1x) + fabsf(e1y));
            float w2 = s * ((cx - a0x) * e2y - (cy - a0y) * e2x) + HEXT * (fabsf(e2x) + fabsf(e2y));
            float l0 = e0x * e0x + e0y * e0y;
            float l1 = e1x * e1x + e1y * e1y;
            float l2 = e2x * e2x + e2y * e2y;
            surv &= !((w0 < 0.0f) & (w0 * w0 > CULL_D2 * l0));
            surv &= !((w1 < 0.0f) & (w1 * w1 > CULL_D2 * l1));
            surv &= !((w2 < 0.0f) & (w2 * w2 > CULL_D2 * l2));
        }
        u64 m = __ballot(surv);
        if (lane == 0) sWc[wave] = (unsigned)__popcll(m);
        __syncthreads();
        int off = scnt;
        for (int w = 0; w < 4; ++w) { if (w < wave) off += (int)sWc[w]; }
        int tot = (int)(sWc[0] + sWc[1] + sWc[2] + sWc[3]);
        if (surv) {
            int pos = off + __popcll(m & ((1ull << lane) - 1ull));
            float* r = &sFD[pos * REC];
            r[0]=a0x; r[1]=a0y; r[2]=a1x; r[3]=a1y; r[4]=a2x; r[5]=a2y;
            r[6]=e0x; r[7]=e0y; r[8]=e1x; r[9]=e1y; r[10]=e2x; r[11]=e2y;
            r[12]=z0; r[13]=z1; r[14]=z2; r[15]=denom;
            // exact dd for the three segment tests (numpy op order):
            r[16] = (e2x * e2x + e2y * e2y) + EPSF;   // seg(a0,a1)
            r[17] = (e0x * e0x + e0y * e0y) + EPSF;   // seg(a1,a2)
            r[18] = (e1x * e1x + e1y * e1y) + EPSF;   // seg(a2,a0)
            r[19] = __int_as_float(fbase + jl);
        }
        scnt += tot;
        __syncthreads();   // records visible; sWc reusable
    }

    // ---- eval survivors: 4 waves stride the record list ----
    u64 s0 = INVK, s1 = INVK, s2 = INVK, s3 = INVK;
    for (int j = wave; j < scnt; j += 4) {
        const float* r = &sFD[j * REC];
        float4 q0 = *(const float4*)(r);
        float4 q1 = *(const float4*)(r + 4);
        float4 q2 = *(const float4*)(r + 8);
        float4 q3 = *(const float4*)(r + 12);
        float4 q4 = *(const float4*)(r + 16);
        float a0x=q0.x, a0y=q0.y, a1x=q0.z, a1y=q0.w, a2x=q1.x, a2y=q1.y;
        float e0x=q1.z, e0y=q1.w, e1x=q2.x, e1y=q2.y, e2x=q2.z, e2y=q2.w;
        float z0=q3.x, z1=q3.y, z2=q3.z, D=q3.w;
        float ddA=q4.x, ddB=q4.y, ddC=q4.z;
        int   fg = __float_as_int(q4.w);
        float p0x = px - a0x, p0y = py - a0y;
        float p1x = px - a1x, p1y = py - a1y;
        float p2x = px - a2x, p2y = py - a2y;
        float w0 = p1x * e0y - p1y * e0x;
        float w1 = p2x * e1y - p2y * e1x;
        float w2 = p0x * e2y - p0y * e2x;
        float b0 = w0 / D, b1 = w1 / D, b2 = w2 / D;    // IEEE divides
        float zpix = (b0 * z0 + b1 * z1) + b2 * z2;     // numpy order
        bool inside = fminf(b0, fminf(b1, b2)) >= 0.0f; // no NaNs possible
        // far gate: all three edge-LINE dist^2 provably > BLUR (conservative)
        bool far = (w0 * w0 > FARC * ddB) & (w1 * w1 > FARC * ddC) & (w2 * w2 > FARC * ddA);
        bool valid;
        if (__all(inside | far)) {
            valid = inside & (zpix > EPSF);
        } else {
            // seg(a0,a1): pa=p0, ab=e2, dd=ddA
            float tA = (p0x * e2x + p0y * e2y) / ddA;
            tA = fminf(fmaxf(tA, 0.0f), 1.0f);
            float dxA = p0x - tA * e2x, dyA = p0y - tA * e2y;
            float dA = dxA * dxA + dyA * dyA;
            // seg(a1,a2): pa=p1, ab=e0, dd=ddB
            float tB = (p1x * e0x + p1y * e0y) / ddB;
            tB = fminf(fmaxf(tB, 0.0f), 1.0f);
            float dxB = p1x - tB * e0x, dyB = p1y - tB * e0y;
            float dB = dxB * dxB + dyB * dyB;
            // seg(a2,a0): pa=p2, ab=e1, dd=ddC
            float tC = (p2x * e1x + p2y * e1y) / ddC;
            tC = fminf(fmaxf(tC, 0.0f), 1.0f);
            float dxC = p2x - tC * e1x, dyC = p2y - tC * e1y;
            float dC = dxC * dxC + dyC * dyC;
            float dmin = fminf(dA, fminf(dB, dC));
            valid = (inside | (dmin < BLURF)) & (zpix > EPSF);
        }
        u64 key = valid ? ((((u64)__float_as_uint(zpix)) << 32) | (unsigned)fg) : INVK;
        if (__any(key < s3)) ins4(s0, s1, s2, s3, key);
    }

    // ---- cross-wave merge: 4 waves -> wave 0, write partial ----
    if (wave >= 2) {
        int r = wave - 2;
        sK[(r * 4 + 0) * 64 + lane] = s0;
        sK[(r * 4 + 1) * 64 + lane] = s1;
        sK[(r * 4 + 2) * 64 + lane] = s2;
        sK[(r * 4 + 3) * 64 + lane] = s3;
    }
    __syncthreads();
    if (wave < 2) {
        ins4(s0, s1, s2, s3, sK[(wave * 4 + 0) * 64 + lane]);
        ins4(s0, s1, s2, s3, sK[(wave * 4 + 1) * 64 + lane]);
        ins4(s0, s1, s2, s3, sK[(wave * 4 + 2) * 64 + lane]);
        ins4(s0, s1, s2, s3, sK[(wave * 4 + 3) * 64 + lane]);
    }
    __syncthreads();
    if (wave == 1) {
        sK[0 * 64 + lane] = s0;
        sK[1 * 64 + lane] = s1;
        sK[2 * 64 + lane] = s2;
        sK[3 * 64 + lane] = s3;
    }
    __syncthreads();
    if (wave == 0) {
        ins4(s0, s1, s2, s3, sK[0 * 64 + lane]);
        ins4(s0, s1, s2, s3, sK[1 * 64 + lane]);
        ins4(s0, s1, s2, s3, sK[2 * 64 + lane]);
        ins4(s0, s1, s2, s3, sK[3 * 64 + lane]);
        u64* wrow = part + (size_t)unit * 256;
        wrow[0 * 64 + lane] = s0;
        wrow[1 * 64 + lane] = s1;
        wrow[2 * 64 + lane] = s2;
        wrow[3 * 64 + lane] = s3;
    }
}

// ---------------- kernel 2: merge slices + exact epilogue ----------------
__global__ __launch_bounds__(256) void raster_p2(
    const float* __restrict__ verts,
    const int*   __restrict__ faces,
    const u64* __restrict__ part,
    int sh,
    float* __restrict__ out0, float* __restrict__ out1,
    float* __restrict__ out2, float* __restrict__ out3)
{
#pragma clang fp contract(off)
    __shared__ u64 sK[4 * 64];
    const int S    = 1 << sh;
    const int tid  = threadIdx.x;
    const int tile = blockIdx.x;
    const int b    = tile >> 8;
    const int trow = (tile & 255) >> 4;
    const int tcol = tile & 15;
    const float* vb = verts + b * NV * 3;

    if (tid < 64) {
        u64 s0 = INVK, s1 = INVK, s2 = INVK, s3 = INVK;
        const u64* base = part + (size_t)tile * S * 256;
        for (int s = 0; s < S; ++s) {
            ins4(s0, s1, s2, s3, base[s * 256 + 0 * 64 + tid]);
            ins4(s0, s1, s2, s3, base[s * 256 + 1 * 64 + tid]);
            ins4(s0, s1, s2, s3, base[s * 256 + 2 * 64 + tid]);
            ins4(s0, s1, s2, s3, base[s * 256 + 3 * 64 + tid]);
        }
        sK[0 * 64 + tid] = s0;
        sK[1 * 64 + tid] = s1;
        sK[2 * 64 + tid] = s2;
        sK[3 * 64 + tid] = s3;
    }
    __syncthreads();

    int pix = tid >> 2, k = tid & 3;
    u64 key = sK[k * 64 + pix];
    int prow = pix >> 3, pcol = pix & 7;
    int grow = trow * 8 + prow, gcol = tcol * 8 + pcol;
    int p = (b * IMG + grow) * IMG + gcol;
    float qx = 1.0f - (2.0f * ((float)gcol + 0.5f)) / 128.0f;
    float qy = 1.0f - (2.0f * ((float)grow + 0.5f)) / 128.0f;
    float o0 = -1.0f, o1 = -1.0f, ob0 = -1.0f, ob1 = -1.0f, ob2 = -1.0f, o3 = -1.0f;
    if ((unsigned)(key >> 32) != 0x7f800000u) {
        int fi = (int)(unsigned)(key & 0xffffffffu);
        int i0 = faces[3 * fi + 0], i1 = faces[3 * fi + 1], i2 = faces[3 * fi + 2];
        float a0x = vb[3 * i0], a0y = vb[3 * i0 + 1], z0 = vb[3 * i0 + 2];
        float a1x = vb[3 * i1], a1y = vb[3 * i1 + 1], z1 = vb[3 * i1 + 2];
        float a2x = vb[3 * i2], a2y = vb[3 * i2 + 1], z2 = vb[3 * i2 + 2];
        float area = (a2x - a0x) * (a1y - a0y) - (a2y - a0y) * (a1x - a0x);
        float aab  = fabsf(area);
        float denom = (aab > EPSF) ? area : (area >= 0.0f ? EPSF : -EPSF);
        float e0x = a2x - a1x, e0y = a2y - a1y;
        float e1x = a0x - a2x, e1y = a0y - a2y;
        float e2x = a1x - a0x, e2y = a1y - a0y;
        float p0x = qx - a0x, p0y = qy - a0y;
        float p1x = qx - a1x, p1y = qy - a1y;
        float p2x = qx - a2x, p2y = qy - a2y;
        float w0 = p1x * e0y - p1y * e0x;
        float w1 = p2x * e1y - p2y * e1x;
        float w2 = p0x * e2y - p0y * e2x;
        float b0 = w0 / denom, b1 = w1 / denom, b2 = w2 / denom;
        float zpix = (b0 * z0 + b1 * z1) + b2 * z2;
        bool inside = (b0 >= 0.0f) & (b1 >= 0.0f) & (b2 >= 0.0f);
        float ddA = (e2x * e2x + e2y * e2y) + EPSF;
        float tA = (p0x * e2x + p0y * e2y) / ddA;
        tA = fminf(fmaxf(tA, 0.0f), 1.0f);
        float dxA = p0x - tA * e2x, dyA = p0y - tA * e2y;
        float dA = dxA * dxA + dyA * dyA;
        float ddB = (e0x * e0x + e0y * e0y) + EPSF;
        float tB = (p1x * e0x + p1y * e0y) / ddB;
        tB = fminf(fmaxf(tB, 0.0f), 1.0f);
        float dxB = p1x - tB * e0x, dyB = p1y - tB * e0y;
        float dB = dxB * dxB + dyB * dyB;
        float ddC = (e1x * e1x + e1y * e1y) + EPSF;
        float tC = (p2x * e1x + p2y * e1y) / ddC;
        tC = fminf(fmaxf(tC, 0.0f), 1.0f);
        float dxC = p2x - tC * e1x, dyC = p2y - tC * e1y;
        float dC = dxC * dxC + dyC * dyC;
        float dmin = fminf(dA, fminf(dB, dC));
        o0 = (float)fi;
        o1 = zpix;
        ob0 = b0; ob1 = b1; ob2 = b2;
        o3 = inside ? -dmin : dmin;
    }
    int o = p * KF + k;
    out0[o] = o0;
    out1[o] = o1;
    out2[o * 3 + 0] = ob0;
    out2[o * 3 + 1] = ob1;
    out2[o * 3 + 2] = ob2;
    out3[o] = o3;
}

extern "C" void kernel_launch(void* const* d_in, const int* in_sizes, int n_in,
                              void* d_out, int out_size, void* d_ws, size_t ws_size,
                              hipStream_t stream) {
    const float* verts = (const float*)d_in[0];
    const int*   faces = (const int*)d_in[1];
    float* out = (float*)d_out;
    const int n0 = NB * IMG * IMG * KF;   // 131072 per (B,H,W,K) output

    // ws: 2 KB partial keys per unit. sh=3 -> 4096 units (8 MB); fallback sh=2.
    const size_t per_unit = 256 * sizeof(u64);
    int sh = (ws_size >= (512ull << 3) * per_unit) ? 3 : 2;
    const int S = 1 << sh;
    const int chunk = NF >> sh;
    const size_t dyn = (size_t)chunk * REC * sizeof(float);
    u64* part = (u64*)d_ws;

    raster_p1<<<dim3(512 * S), dim3(256), dyn, stream>>>(verts, faces, part, sh);
    raster_p2<<<dim3(512), dim3(256), 0, stream>>>(verts, faces, part, sh,
        out,                 // pix_to_face
        out + n0,            // zbuf
        out + 2 * n0,        // bary
        out + 5 * n0);       // dsign
}